// Round 4
// baseline (400.454 us; speedup 1.0000x reference)
//
#include <hip/hip_runtime.h>
#include <hip/hip_bf16.h>
#include <hip/hip_fp16.h>
#include <cmath>

#define NTOK 16384
#define KDIM 1024
#define NDIM 2048
#define NSTK 4
#define SDIM 256

typedef __attribute__((ext_vector_type(8))) _Float16 f16x8;
typedef __attribute__((ext_vector_type(4))) float f32x4;

static __device__ __forceinline__ unsigned short f2h(float f) {
  union { _Float16 h; unsigned short u; } v;
  v.h = (_Float16)f;
  return v.u;
}

#define ASCL 16.0f
#define BSCL 32.0f
#define ABSCL 512.0f  // ASCL*BSCL

// ---------------- K0: per-output-column params + zero m-tile counters ----------------
__global__ void prep_cols(const float* __restrict__ wg, const float* __restrict__ bias,
                          const float* __restrict__ cptr, float* __restrict__ colp,
                          int* __restrict__ counters) {
  int j = blockIdx.x * 256 + threadIdx.x;
  if (blockIdx.x == 0 && threadIdx.x < 64) counters[threadIdx.x] = 0;
  if (j >= NDIM) return;
  float c = cptr[0];
  float rc = sqrtf(c);
  float w = wg[j];
  float invn = 1.0f / fmaxf(w, 1e-15f);
  float drcr = 2.0f * rc * bias[j];
  float ed = expf(drcr);
  float edi = 1.0f / ed;
  float coshd = 0.5f * (ed + edi);
  float sinhd = 0.5f * (ed - edi);
  colp[4 * j + 0] = 2.0f * invn * coshd / ABSCL;
  colp[4 * j + 1] = sinhd;
  colp[4 * j + 2] = 2.0f * w;
  colp[4 * j + 3] = 0.0f;
}

// ---------------- K1: transpose weight_v [K][N] -> Bt fp16 [N][K] (x BSCL) ----------------
__global__ void transpose_w(const float* __restrict__ wv, unsigned short* __restrict__ Bt) {
  __shared__ float tile[32][33];
  int n0 = blockIdx.x * 32;
  int k0 = blockIdx.y * 32;
  int tx = threadIdx.x;
  int ty = threadIdx.y;
  for (int i = 0; i < 32; i += 8)
    tile[ty + i][tx] = wv[(long)(k0 + ty + i) * NDIM + n0 + tx];
  __syncthreads();
  for (int i = 0; i < 32; i += 8)
    Bt[(long)(n0 + ty + i) * KDIM + k0 + tx] = f2h(tile[tx][ty + i] * BSCL);
}

// ---------------- K2: per-token analytic scale -> A fp16 (= rcx * ASCL), cx2 ----------------
__global__ __launch_bounds__(256) void prep_x(const float* __restrict__ x, const float* __restrict__ cptr,
                                              unsigned short* __restrict__ A, float* __restrict__ cx2out,
                                              float Rbeta) {
  int w = threadIdx.x >> 6, lane = threadIdx.x & 63;
  int tok = blockIdx.x * 4 + w;
  const float4* x4 = (const float4*)x;
  float4 v[NSTK];
  float ss[NSTK];
  for (int s = 0; s < NSTK; s++) {
    float4 t = x4[(long)tok * 256 + s * 64 + lane];
    v[s] = t;
    float d = t.x * t.x + t.y * t.y + t.z * t.z + t.w * t.w;
    for (int m = 1; m < 64; m <<= 1) d += __shfl_xor(d, m);
    ss[s] = d;
  }
  float c = cptr[0];
  float rc = sqrtf(c);
  float h[NSTK], un[NSTK], hs2 = 0.0f;
  for (int s = 0; s < NSTK; s++) {
    un[s] = fmaxf(sqrtf(ss[s]), 1e-15f);
    float t1 = fminf(tanhf(rc * un[s]), 0.996f);
    float z = fminf(t1, 1.0f - 1e-7f);
    float hh = 0.5f * logf((1.0f + z) / (1.0f - z));
    h[s] = hh;
    hs2 += hh * hh;
  }
  float sqh = sqrtf(hs2);
  float uwrc = Rbeta * sqh;
  float t2 = fminf(tanhf(uwrc), 0.996f);
  if (lane == 0) cx2out[tok] = t2 * t2;
  float denomw = fmaxf(uwrc, rc * 1e-15f);
  for (int s = 0; s < NSTK; s++) {
    float scl = ASCL * Rbeta * h[s] * t2 / (un[s] * denomw);
    float4 t = v[s];
    ushort4 pk = make_ushort4(f2h(t.x * scl), f2h(t.y * scl), f2h(t.z * scl), f2h(t.w * scl));
    *(ushort4*)&A[(long)tok * KDIM + s * SDIM + lane * 4] = pk;
  }
}

// ---------------- K3: 256x256 8-phase fp16 MFMA GEMM + epilogue + last-block row scaling ----------------
#define BK 64
#define NKT (KDIM / BK)  // 16

#define GLDS16(g, l)                                                              \
  __builtin_amdgcn_global_load_lds((const __attribute__((address_space(1))) void*)(g), \
                                   (__attribute__((address_space(3))) void*)(l), 16, 0, 0)

#define PH_BARRIER __builtin_amdgcn_s_barrier()
#define PRIO1 __builtin_amdgcn_s_setprio(1)
#define PRIO0 __builtin_amdgcn_s_setprio(0)
#define LGKM0                                                  \
  do {                                                         \
    asm volatile("s_waitcnt lgkmcnt(0)" ::: "memory");         \
    __builtin_amdgcn_sched_barrier(0);                         \
  } while (0)
#define VMCNT6 asm volatile("s_waitcnt vmcnt(6)" ::: "memory")
#define VMCNT0 asm volatile("s_waitcnt vmcnt(0)" ::: "memory")

#define ISSUE_A(T, H)                                                        \
  do {                                                                       \
    const unsigned short* _s = Asrc + (long)(H) * (128 * KDIM) + (T) * BK;   \
    unsigned char* _d = lds + (((T) & 1) * 32768 + (H) * 16384) + tid * 16;  \
    GLDS16(_s, _d);                                                          \
    GLDS16(_s + 64 * KDIM, _d + 8192);                                       \
  } while (0)
#define ISSUE_B(T, H)                                                        \
  do {                                                                       \
    const unsigned short* _s = Bsrc + (long)(H) * (128 * KDIM) + (T) * BK;   \
    unsigned char* _d = lds + 65536 + (((T) & 1) * 32768 + (H) * 16384) + tid * 16; \
    GLDS16(_s, _d);                                                          \
    GLDS16(_s + 64 * KDIM, _d + 8192);                                       \
  } while (0)

#define READ_A(BUFOFF, FMB)                                                  \
  _Pragma("unroll") for (int fm = 0; fm < 4; ++fm)                           \
    _Pragma("unroll") for (int ks = 0; ks < 2; ++ks)                         \
      aF[fm][ks] = *(const f16x8*)(lds + (BUFOFF) + aBase + ((FMB) + fm) * 2048 + chunk[ks]);
#define READ_B(BUFOFF)                                                       \
  _Pragma("unroll") for (int fn = 0; fn < 4; ++fn)                           \
    _Pragma("unroll") for (int ks = 0; ks < 2; ++ks)                         \
      bF[fn][ks] = *(const f16x8*)(lds + 65536 + (BUFOFF) + bBase + fn * 2048 + chunk[ks]);

#define MFMA_Q(FM0, FN0)                                                     \
  _Pragma("unroll") for (int fi = 0; fi < 4; ++fi)                           \
    _Pragma("unroll") for (int fj = 0; fj < 2; ++fj)                         \
      _Pragma("unroll") for (int ks = 0; ks < 2; ++ks)                       \
        acc[(FM0) + fi][(FN0) + fj] = __builtin_amdgcn_mfma_f32_16x16x32_f16( \
            aF[fi][ks], bF[(FN0) + fj][ks], acc[(FM0) + fi][(FN0) + fj], 0, 0, 0);

#define TILE(BUFOFF, T, GA, GE, VMODE)                                       \
  do {                                                                       \
    READ_A(BUFOFF, 0);                                                       \
    READ_B(BUFOFF);                                                          \
    if (GA) ISSUE_A((T) + 1, 1);                                             \
    PH_BARRIER;                                                              \
    LGKM0;                                                                   \
    PRIO1; MFMA_Q(0, 0); PRIO0;                                              \
    PH_BARRIER;                                                              \
    if (GE) ISSUE_B((T) + 2, 0);                                             \
    PH_BARRIER;                                                              \
    PRIO1; MFMA_Q(0, 2); PRIO0;                                              \
    PH_BARRIER;                                                              \
    READ_A(BUFOFF, 4);                                                       \
    if (GE) ISSUE_B((T) + 2, 1);                                             \
    PH_BARRIER;                                                              \
    LGKM0;                                                                   \
    PRIO1; MFMA_Q(4, 0); PRIO0;                                              \
    PH_BARRIER;                                                              \
    if (GE) ISSUE_A((T) + 2, 0);                                             \
    if ((VMODE) == 0) { VMCNT6; } else if ((VMODE) == 1) { VMCNT0; }         \
    PH_BARRIER;                                                              \
    PRIO1; MFMA_Q(4, 2); PRIO0;                                              \
    PH_BARRIER;                                                              \
  } while (0)

__global__ __launch_bounds__(512, 2) void gemm_ep(const unsigned short* __restrict__ A,
                                                  const unsigned short* __restrict__ Bt,
                                                  const float* __restrict__ cx2,
                                                  const float* __restrict__ colp,
                                                  const float* __restrict__ cptr,
                                                  float* __restrict__ outY,
                                                  int* __restrict__ counters) {
  __shared__ __attribute__((aligned(16))) unsigned char lds[131072];
  __shared__ int sIsLast;
  int tid = threadIdx.x;
  int lane = tid & 63, w = tid >> 6;
  int wm = w >> 2, wn = w & 3;          // 2 x 4 waves; per-wave out 128x64
  int g = lane >> 4, r = lane & 15;
  int bid = blockIdx.x;
  // XCD-chunked swizzle: each XCD owns 8 consecutive m-panels x all 8 n-tiles,
  // n-major within XCD so the co-resident half shares A-panels and all of B.
  int xcd = bid & 7, idx = bid >> 3;
  int tile_m = xcd * 8 + (idx >> 3);
  int tile_n = idx & 7;
  int m0 = tile_m * 256, n0 = tile_n * 256;

  int srow = tid >> 3;
  int csrc = ((tid & 7) ^ (srow & 7)) << 3;
  const unsigned short* Asrc = A + (long)(m0 + srow) * KDIM + csrc;
  const unsigned short* Bsrc = Bt + (long)(n0 + srow) * KDIM + csrc;

  int aBase = wm * 16384 + r * 128;
  int bBase = (wn >> 1) * 16384 + (wn & 1) * 8192 + r * 128;
  int chunk[2];
  chunk[0] = ((0 * 4 + g) ^ (r & 7)) * 16;
  chunk[1] = ((1 * 4 + g) ^ (r & 7)) * 16;

  f32x4 acc[8][4];
#pragma unroll
  for (int i = 0; i < 8; i++)
#pragma unroll
    for (int j = 0; j < 4; j++) acc[i][j] = (f32x4){0.f, 0.f, 0.f, 0.f};
  f16x8 aF[4][2], bF[4][2];

  ISSUE_A(0, 0); ISSUE_A(0, 1); ISSUE_B(0, 0); ISSUE_B(0, 1);
  ISSUE_B(1, 0); ISSUE_B(1, 1); ISSUE_A(1, 0);
  VMCNT6;
  PH_BARRIER;

#pragma unroll 1
  for (int it = 0; it < NKT / 2 - 1; ++it) {
    TILE(0, 2 * it, true, true, 0);
    TILE(32768, 2 * it + 1, true, true, 0);
  }
  TILE(0, NKT - 2, true, false, 1);
  TILE(32768, NKT - 1, false, false, 2);

  // epilogue: y = sinh(2*wg*arsinh(num/(1-cx2)))/rc, stored UNscaled
  float c = cptr[0];
  float rc = sqrtf(c);
  float inv_rc = 1.0f / rc;
  const float4* cp4 = (const float4*)colp;
#pragma unroll
  for (int fm = 0; fm < 8; ++fm) {
#pragma unroll
    for (int q = 0; q < 4; ++q) {
      int row = m0 + wm * 128 + fm * 16 + g * 4 + q;
      float cx = cx2[row];
      float onec = 1.0f + cx;
      float rdn = 1.0f / fmaxf(1.0f - cx, 1e-15f);
#pragma unroll
      for (int fn = 0; fn < 4; ++fn) {
        int col = n0 + wn * 64 + fn * 16 + r;
        float4 cp = cp4[col];
        float dot = acc[fm][fn][q];
        float num = fmaf(dot, cp.x, -onec * cp.y);
        float u = num * rdn;
        float au = fabsf(u);
        float as = __logf(au + sqrtf(fmaf(au, au, 1.0f)));
        as = copysignf(as, u);
        float s2 = cp.z * as;
        float ex = __expf(s2);
        float exi = __builtin_amdgcn_rcpf(ex);
        float y = 0.5f * (ex - exi) * inv_rc;
        outY[(long)row * NDIM + col] = y;
      }
    }
  }

  // last-of-8 block for this m-tile scales the full 256 x 2048 slice in place
  __threadfence();
  __syncthreads();
  if (tid == 0) {
    int old = atomicAdd(&counters[tile_m], 1);
    sIsLast = (old == 7) ? 1 : 0;
  }
  __syncthreads();
  if (sIsLast) {
    __threadfence();  // acquire: invalidate L1 before reading peers' stores
    float maxn = (c > 0.0f) ? 0.996f / sqrtf(fmaxf(c, 1e-15f)) : 1e15f;
    for (int rr = w; rr < 256; rr += 8) {
      long base = (long)(m0 + rr) * NDIM;
      float4* yrow = (float4*)(outY + base);
      float s = 0.0f;
#pragma unroll
      for (int itp = 0; itp < 8; ++itp) {
        float4 v = yrow[itp * 64 + lane];
        s = fmaf(v.x, v.x, fmaf(v.y, v.y, fmaf(v.z, v.z, fmaf(v.w, v.w, s))));
      }
      for (int m = 1; m < 64; m <<= 1) s += __shfl_xor(s, m);
      float denom = 1.0f + sqrtf(fmaf(c, s, 1.0f));
      float nv = fmaxf(sqrtf(s) / denom, 1e-15f);
      float scl = (nv > maxn) ? (maxn / (nv * denom)) : (1.0f / denom);
#pragma unroll
      for (int itp = 0; itp < 8; ++itp) {
        float4 v = yrow[itp * 64 + lane];
        v.x *= scl; v.y *= scl; v.z *= scl; v.w *= scl;
        yrow[itp * 64 + lane] = v;
      }
    }
  }
}

extern "C" void kernel_launch(void* const* d_in, const int* in_sizes, int n_in,
                              void* d_out, int out_size, void* d_ws, size_t ws_size,
                              hipStream_t stream) {
  const float* x = (const float*)d_in[0];
  const float* wg = (const float*)d_in[1];
  const float* wv = (const float*)d_in[2];
  const float* bias = (const float*)d_in[3];
  const float* cpt = (const float*)d_in[4];
  float* out = (float*)d_out;

  char* ws = (char*)d_ws;
  unsigned short* A = (unsigned short*)ws;                    // 33,554,432 B
  unsigned short* Bt = (unsigned short*)(ws + 33554432);      //  4,194,304 B
  float* cx2 = (float*)(ws + 37748736);                       //     65,536 B
  float* colp = (float*)(ws + 37814272);                      //     32,768 B
  int* counters = (int*)(ws + 37847040);                      //        256 B

  double lbni = lgamma(128.0) + lgamma(0.5) - lgamma(128.5);
  double lbn = lgamma(512.0) + lgamma(0.5) - lgamma(512.5);
  float Rbeta = (float)exp(lbn - lbni);

  prep_cols<<<8, 256, 0, stream>>>(wg, bias, cpt, colp, counters);
  transpose_w<<<dim3(64, 32), dim3(32, 8), 0, stream>>>(wv, Bt);
  prep_x<<<4096, 256, 0, stream>>>(x, cpt, A, cx2, Rbeta);
  gemm_ep<<<512, 512, 0, stream>>>(A, Bt, cx2, colp, cpt, out, counters);
}

// Round 5
// 183.603 us; speedup vs baseline: 2.1811x; 2.1811x over previous
//
#include <hip/hip_runtime.h>
#include <hip/hip_bf16.h>
#include <hip/hip_fp16.h>
#include <cmath>

#define NTOK 16384
#define KDIM 1024
#define NDIM 2048
#define NSTK 4
#define SDIM 256

typedef __attribute__((ext_vector_type(8))) _Float16 f16x8;
typedef __attribute__((ext_vector_type(4))) float f32x4;

static __device__ __forceinline__ unsigned short f2h(float f) {
  union { _Float16 h; unsigned short u; } v;
  v.h = (_Float16)f;
  return v.u;
}

#define ASCL 16.0f
#define BSCL 32.0f
#define ABSCL 512.0f  // ASCL*BSCL

// ---------------- K0: per-output-column params ----------------
__global__ void prep_cols(const float* __restrict__ wg, const float* __restrict__ bias,
                          const float* __restrict__ cptr, float* __restrict__ colp) {
  int j = blockIdx.x * 256 + threadIdx.x;
  if (j >= NDIM) return;
  float c = cptr[0];
  float rc = sqrtf(c);
  float w = wg[j];
  float invn = 1.0f / fmaxf(w, 1e-15f);
  float drcr = 2.0f * rc * bias[j];
  float ed = expf(drcr);
  float edi = 1.0f / ed;
  float coshd = 0.5f * (ed + edi);
  float sinhd = 0.5f * (ed - edi);
  colp[4 * j + 0] = 2.0f * invn * coshd / ABSCL;
  colp[4 * j + 1] = sinhd;
  colp[4 * j + 2] = 2.0f * w;
  colp[4 * j + 3] = 0.0f;
}

// ---------------- K1: transpose weight_v [K][N] -> Bt fp16 [N][K] (x BSCL) ----------------
__global__ void transpose_w(const float* __restrict__ wv, unsigned short* __restrict__ Bt) {
  __shared__ float tile[32][33];
  int n0 = blockIdx.x * 32;
  int k0 = blockIdx.y * 32;
  int tx = threadIdx.x;
  int ty = threadIdx.y;
  for (int i = 0; i < 32; i += 8)
    tile[ty + i][tx] = wv[(long)(k0 + ty + i) * NDIM + n0 + tx];
  __syncthreads();
  for (int i = 0; i < 32; i += 8)
    Bt[(long)(n0 + ty + i) * KDIM + k0 + tx] = f2h(tile[tx][ty + i] * BSCL);
}

// ---------------- K2: per-token analytic scale -> A fp16 (= rcx * ASCL), cx2 ----------------
__global__ __launch_bounds__(256) void prep_x(const float* __restrict__ x, const float* __restrict__ cptr,
                                              unsigned short* __restrict__ A, float* __restrict__ cx2out,
                                              float Rbeta) {
  int w = threadIdx.x >> 6, lane = threadIdx.x & 63;
  int tok = blockIdx.x * 4 + w;
  const float4* x4 = (const float4*)x;
  float4 v[NSTK];
  float ss[NSTK];
  for (int s = 0; s < NSTK; s++) {
    float4 t = x4[(long)tok * 256 + s * 64 + lane];
    v[s] = t;
    float d = t.x * t.x + t.y * t.y + t.z * t.z + t.w * t.w;
    for (int m = 1; m < 64; m <<= 1) d += __shfl_xor(d, m);
    ss[s] = d;
  }
  float c = cptr[0];
  float rc = sqrtf(c);
  float h[NSTK], un[NSTK], hs2 = 0.0f;
  for (int s = 0; s < NSTK; s++) {
    un[s] = fmaxf(sqrtf(ss[s]), 1e-15f);
    float t1 = fminf(tanhf(rc * un[s]), 0.996f);
    float z = fminf(t1, 1.0f - 1e-7f);
    float hh = 0.5f * logf((1.0f + z) / (1.0f - z));
    h[s] = hh;
    hs2 += hh * hh;
  }
  float sqh = sqrtf(hs2);
  float uwrc = Rbeta * sqh;
  float t2 = fminf(tanhf(uwrc), 0.996f);
  if (lane == 0) cx2out[tok] = t2 * t2;
  float denomw = fmaxf(uwrc, rc * 1e-15f);
  for (int s = 0; s < NSTK; s++) {
    float scl = ASCL * Rbeta * h[s] * t2 / (un[s] * denomw);
    float4 t = v[s];
    ushort4 pk = make_ushort4(f2h(t.x * scl), f2h(t.y * scl), f2h(t.z * scl), f2h(t.w * scl));
    *(ushort4*)&A[(long)tok * KDIM + s * SDIM + lane * 4] = pk;
  }
}

// ---------------- K3: 256x256 8-phase fp16 MFMA GEMM, balanced reads ----------------
#define BK 64
#define NKT (KDIM / BK)  // 16

#define GLDS16(g, l)                                                              \
  __builtin_amdgcn_global_load_lds((const __attribute__((address_space(1))) void*)(g), \
                                   (__attribute__((address_space(3))) void*)(l), 16, 0, 0)

#define PH_BARRIER __builtin_amdgcn_s_barrier()
#define PRIO1 __builtin_amdgcn_s_setprio(1)
#define PRIO0 __builtin_amdgcn_s_setprio(0)
#define LGKM0                                                  \
  do {                                                         \
    asm volatile("s_waitcnt lgkmcnt(0)" ::: "memory");         \
    __builtin_amdgcn_sched_barrier(0);                         \
  } while (0)
#define VMCNT4 asm volatile("s_waitcnt vmcnt(4)" ::: "memory")
#define VMCNT0 asm volatile("s_waitcnt vmcnt(0)" ::: "memory")

#define ISSUE_A(T, H)                                                        \
  do {                                                                       \
    const unsigned short* _s = Asrc + (long)(H) * (128 * KDIM) + (T) * BK;   \
    unsigned char* _d = lds + (((T) & 1) * 32768 + (H) * 16384) + tid * 16;  \
    GLDS16(_s, _d);                                                          \
    GLDS16(_s + 64 * KDIM, _d + 8192);                                       \
  } while (0)
#define ISSUE_B(T, H)                                                        \
  do {                                                                       \
    const unsigned short* _s = Bsrc + (long)(H) * (128 * KDIM) + (T) * BK;   \
    unsigned char* _d = lds + 65536 + (((T) & 1) * 32768 + (H) * 16384) + tid * 16; \
    GLDS16(_s, _d);                                                          \
    GLDS16(_s + 64 * KDIM, _d + 8192);                                       \
  } while (0)

// 4 ds_read_b128 each: one K-slice (ks) of 4 fragments
#define READ_A4(BUFOFF, FMB, KS)                                             \
  _Pragma("unroll") for (int fm = 0; fm < 4; ++fm)                           \
    aF[fm][KS] = *(const f16x8*)(lds + (BUFOFF) + aBase + ((FMB) + fm) * 2048 + chunk[KS]);
#define READ_B4(BUFOFF, KS)                                                  \
  _Pragma("unroll") for (int fn = 0; fn < 4; ++fn)                           \
    bF[fn][KS] = *(const f16x8*)(lds + 65536 + (BUFOFF) + bBase + fn * 2048 + chunk[KS]);

// 16 MFMA: fm block (FM0..FM0+3) x all 4 fn, one K-slice
#define MFMA_PH(FM0, KS)                                                     \
  _Pragma("unroll") for (int fi = 0; fi < 4; ++fi)                           \
    _Pragma("unroll") for (int fj = 0; fj < 4; ++fj)                         \
      acc[(FM0) + fi][fj] = __builtin_amdgcn_mfma_f32_16x16x32_f16(          \
          aF[fi][KS], bF[fj][KS], acc[(FM0) + fi][fj], 0, 0, 0);

// One K-tile = 4 phases, 8/8/4/4 ds_reads, 16 MFMA each.
// Issues: A(T+1) halves at P1/P2 (opposite LDS buf - always safe);
// B(T+2) halves at P3/P4 (own buf, but B regs fully loaded by P2's lgkm).
// VMODE: 0 -> vmcnt(4) at P4 (steady); 1 -> vmcnt(0); 2 -> none.
#define TILE(BUFOFF, T, GA, GB, VMODE)                                       \
  do {                                                                       \
    READ_A4(BUFOFF, 0, 0); READ_B4(BUFOFF, 0);                               \
    if (GA) ISSUE_A((T) + 1, 0);                                             \
    PH_BARRIER; LGKM0;                                                       \
    PRIO1; MFMA_PH(0, 0); PRIO0;                                             \
    PH_BARRIER;                                                              \
    READ_A4(BUFOFF, 0, 1); READ_B4(BUFOFF, 1);                               \
    if (GA) ISSUE_A((T) + 1, 1);                                             \
    PH_BARRIER; LGKM0;                                                       \
    PRIO1; MFMA_PH(0, 1); PRIO0;                                             \
    PH_BARRIER;                                                              \
    READ_A4(BUFOFF, 4, 0);                                                   \
    if (GB) ISSUE_B((T) + 2, 0);                                             \
    PH_BARRIER; LGKM0;                                                       \
    PRIO1; MFMA_PH(4, 0); PRIO0;                                             \
    PH_BARRIER;                                                              \
    READ_A4(BUFOFF, 4, 1);                                                   \
    if (GB) ISSUE_B((T) + 2, 1);                                             \
    if ((VMODE) == 0) { VMCNT4; } else if ((VMODE) == 1) { VMCNT0; }         \
    PH_BARRIER; LGKM0;                                                       \
    PRIO1; MFMA_PH(4, 1); PRIO0;                                             \
    PH_BARRIER;                                                              \
  } while (0)

template <int F16S>
__global__ __launch_bounds__(512, 2) void gemm_ep(const unsigned short* __restrict__ A,
                                                  const unsigned short* __restrict__ Bt,
                                                  const float* __restrict__ cx2,
                                                  const float* __restrict__ colp,
                                                  const float* __restrict__ cptr,
                                                  float* __restrict__ outY,
                                                  unsigned short* __restrict__ y16,
                                                  float* __restrict__ partials) {
  __shared__ __attribute__((aligned(16))) unsigned char lds[131072];
  int tid = threadIdx.x;
  int lane = tid & 63, w = tid >> 6;
  int wm = w >> 2, wn = w & 3;  // 2 x 4 waves; per-wave out 128x64
  int g = lane >> 4, r = lane & 15;
  int bid = blockIdx.x;
  int tile_n = bid & 7, tile_m = bid >> 3;
  int m0 = tile_m * 256, n0 = tile_n * 256;

  int srow = tid >> 3;
  int csrc = ((tid & 7) ^ (srow & 7)) << 3;
  const unsigned short* Asrc = A + (long)(m0 + srow) * KDIM + csrc;
  const unsigned short* Bsrc = Bt + (long)(n0 + srow) * KDIM + csrc;

  int aBase = wm * 16384 + r * 128;
  int bBase = (wn >> 1) * 16384 + (wn & 1) * 8192 + r * 128;
  int chunk[2];
  chunk[0] = ((0 * 4 + g) ^ (r & 7)) * 16;
  chunk[1] = ((1 * 4 + g) ^ (r & 7)) * 16;

  f32x4 acc[8][4];
#pragma unroll
  for (int i = 0; i < 8; i++)
#pragma unroll
    for (int j = 0; j < 4; j++) acc[i][j] = (f32x4){0.f, 0.f, 0.f, 0.f};
  f16x8 aF[4][2], bF[4][2];

  // prologue: tile0 all halves + tile1 B; A(1,*) issued inside tile0's P1/P2
  ISSUE_A(0, 0); ISSUE_A(0, 1); ISSUE_B(0, 0); ISSUE_B(0, 1);
  ISSUE_B(1, 0); ISSUE_B(1, 1);
  VMCNT4;  // tile0's 8 loads landed; tile1 B in flight
  PH_BARRIER;

#pragma unroll 1
  for (int it = 0; it < 7; ++it) {
    TILE(0, 2 * it, 1, 1, 0);
    TILE(32768, 2 * it + 1, 1, 1, 0);
  }
  TILE(0, 14, 1, 0, 1);       // vmcnt(0): tile15 fully landed
  TILE(32768, 15, 0, 0, 2);

  // epilogue: y = sinh(2*wg*arsinh(num/(1-cx2)))/rc, unscaled; row-sumsq partials
  float c = cptr[0];
  float rc = sqrtf(c);
  float inv_rc = 1.0f / rc;
  const float4* cp4 = (const float4*)colp;
  int tn4 = tile_n * 4 + wn;
#pragma unroll
  for (int fm = 0; fm < 8; ++fm) {
#pragma unroll
    for (int q = 0; q < 4; ++q) {
      int row = m0 + wm * 128 + fm * 16 + g * 4 + q;
      float cx = cx2[row];
      float onec = 1.0f + cx;
      float rdn = 1.0f / fmaxf(1.0f - cx, 1e-15f);
      float rs = 0.0f;
#pragma unroll
      for (int fn = 0; fn < 4; ++fn) {
        int col = n0 + wn * 64 + fn * 16 + r;
        float4 cp = cp4[col];
        float dot = acc[fm][fn][q];
        float num = fmaf(dot, cp.x, -onec * cp.y);
        float u = num * rdn;
        float au = fabsf(u);
        float as = __logf(au + sqrtf(fmaf(au, au, 1.0f)));
        as = copysignf(as, u);
        float s2 = cp.z * as;
        float ex = __expf(s2);
        float exi = __builtin_amdgcn_rcpf(ex);
        float y = 0.5f * (ex - exi) * inv_rc;
        if (F16S)
          y16[(long)row * NDIM + col] = f2h(y);
        else
          outY[(long)row * NDIM + col] = y;
        rs = fmaf(y, y, rs);
      }
      rs += __shfl_xor(rs, 1);
      rs += __shfl_xor(rs, 2);
      rs += __shfl_xor(rs, 4);
      rs += __shfl_xor(rs, 8);
      if (r == 0) partials[(long)row * 32 + tn4] = rs;
    }
  }
}

// ---------------- K4a: row scale from partials, apply from fp16 scratch ----------------
__global__ __launch_bounds__(256) void finalize16(const unsigned short* __restrict__ y16,
                                                  const float* __restrict__ partials,
                                                  const float* __restrict__ cptr,
                                                  float* __restrict__ out) {
  int w = threadIdx.x >> 6, lane = threadIdx.x & 63;
  int row = blockIdx.x * 4 + w;
  float p = (lane < 32) ? partials[(long)row * 32 + lane] : 0.0f;
  for (int m = 1; m < 64; m <<= 1) p += __shfl_xor(p, m);
  float c = cptr[0];
  float S = p;
  float denom = 1.0f + sqrtf(fmaf(c, S, 1.0f));
  float nv = fmaxf(sqrtf(S) / denom, 1e-15f);
  float maxn = (c > 0.0f) ? 0.996f / sqrtf(fmaxf(c, 1e-15f)) : 1e15f;
  float scl = (nv > maxn) ? (maxn / (nv * denom)) : (1.0f / denom);
  const f16x8* yr = (const f16x8*)(y16 + (long)row * NDIM);
  float4* o4 = (float4*)(out + (long)row * NDIM);
#pragma unroll
  for (int it = 0; it < 4; ++it) {
    f16x8 v = yr[it * 64 + lane];
    float4 a, b;
    a.x = (float)v[0] * scl; a.y = (float)v[1] * scl;
    a.z = (float)v[2] * scl; a.w = (float)v[3] * scl;
    b.x = (float)v[4] * scl; b.y = (float)v[5] * scl;
    b.z = (float)v[6] * scl; b.w = (float)v[7] * scl;
    o4[(it * 64 + lane) * 2] = a;
    o4[(it * 64 + lane) * 2 + 1] = b;
  }
}

// ---------------- K4b: fallback, in place on fp32 d_out ----------------
__global__ __launch_bounds__(256) void finalize32(float* __restrict__ out,
                                                  const float* __restrict__ partials,
                                                  const float* __restrict__ cptr) {
  int w = threadIdx.x >> 6, lane = threadIdx.x & 63;
  int row = blockIdx.x * 4 + w;
  float p = (lane < 32) ? partials[(long)row * 32 + lane] : 0.0f;
  for (int m = 1; m < 64; m <<= 1) p += __shfl_xor(p, m);
  float c = cptr[0];
  float S = p;
  float denom = 1.0f + sqrtf(fmaf(c, S, 1.0f));
  float nv = fmaxf(sqrtf(S) / denom, 1e-15f);
  float maxn = (c > 0.0f) ? 0.996f / sqrtf(fmaxf(c, 1e-15f)) : 1e15f;
  float scl = (nv > maxn) ? (maxn / (nv * denom)) : (1.0f / denom);
  float4* o4 = (float4*)(out + (long)row * NDIM);
  for (int it = 0; it < NDIM / 256; ++it) {
    float4 v = o4[it * 64 + lane];
    v.x *= scl; v.y *= scl; v.z *= scl; v.w *= scl;
    o4[it * 64 + lane] = v;
  }
}

extern "C" void kernel_launch(void* const* d_in, const int* in_sizes, int n_in,
                              void* d_out, int out_size, void* d_ws, size_t ws_size,
                              hipStream_t stream) {
  const float* x = (const float*)d_in[0];
  const float* wg = (const float*)d_in[1];
  const float* wv = (const float*)d_in[2];
  const float* bias = (const float*)d_in[3];
  const float* cpt = (const float*)d_in[4];
  float* out = (float*)d_out;

  char* ws = (char*)d_ws;
  unsigned short* A = (unsigned short*)ws;                    // 33,554,432 B
  unsigned short* Bt = (unsigned short*)(ws + 33554432);      //  4,194,304 B
  float* cx2 = (float*)(ws + 37748736);                       //     65,536 B
  float* colp = (float*)(ws + 37814272);                      //     32,768 B
  float* parts = (float*)(ws + 37847040);                     //  2,097,152 B
  unsigned short* Y16 = (unsigned short*)(ws + 39944192);     // 67,108,864 B
  const size_t NEED_F16S = 39944192ull + 67108864ull;

  double lbni = lgamma(128.0) + lgamma(0.5) - lgamma(128.5);
  double lbn = lgamma(512.0) + lgamma(0.5) - lgamma(512.5);
  float Rbeta = (float)exp(lbn - lbni);

  prep_cols<<<8, 256, 0, stream>>>(wg, bias, cpt, colp);
  transpose_w<<<dim3(64, 32), dim3(32, 8), 0, stream>>>(wv, Bt);
  prep_x<<<4096, 256, 0, stream>>>(x, cpt, A, cx2, Rbeta);
  if (ws_size >= NEED_F16S) {
    gemm_ep<1><<<512, 512, 0, stream>>>(A, Bt, cx2, colp, cpt, out, Y16, parts);
    finalize16<<<4096, 256, 0, stream>>>(Y16, parts, cpt, out);
  } else {
    gemm_ep<0><<<512, 512, 0, stream>>>(A, Bt, cx2, colp, cpt, out, Y16, parts);
    finalize32<<<4096, 256, 0, stream>>>(out, parts, cpt);
  }
}

// Round 7
// 173.392 us; speedup vs baseline: 2.3095x; 1.0589x over previous
//
#include <hip/hip_runtime.h>
#include <hip/hip_bf16.h>
#include <hip/hip_fp16.h>
#include <cmath>

#define NTOK 16384
#define KDIM 1024
#define NDIM 2048
#define NSTK 4
#define SDIM 256

typedef __attribute__((ext_vector_type(8))) _Float16 f16x8;
typedef __attribute__((ext_vector_type(4))) float f32x4;

static __device__ __forceinline__ unsigned short f2h(float f) {
  union { _Float16 h; unsigned short u; } v;
  v.h = (_Float16)f;
  return v.u;
}

#define ASCL 16.0f
#define BSCL 32.0f
#define ABSCL 512.0f  // ASCL*BSCL

// ---------------- K0: per-output-column params ----------------
__global__ void prep_cols(const float* __restrict__ wg, const float* __restrict__ bias,
                          const float* __restrict__ cptr, float* __restrict__ colp) {
  int j = blockIdx.x * 256 + threadIdx.x;
  if (j >= NDIM) return;
  float c = cptr[0];
  float rc = sqrtf(c);
  float w = wg[j];
  float invn = 1.0f / fmaxf(w, 1e-15f);
  float drcr = 2.0f * rc * bias[j];
  float ed = expf(drcr);
  float edi = 1.0f / ed;
  float coshd = 0.5f * (ed + edi);
  float sinhd = 0.5f * (ed - edi);
  colp[4 * j + 0] = 2.0f * invn * coshd / ABSCL;
  colp[4 * j + 1] = sinhd;
  colp[4 * j + 2] = 2.0f * w;
  colp[4 * j + 3] = 0.0f;
}

// ---------------- K1: transpose weight_v [K][N] -> Bt fp16 [N][K] (x BSCL) ----------------
__global__ void transpose_w(const float* __restrict__ wv, unsigned short* __restrict__ Bt) {
  __shared__ float tile[32][33];
  int n0 = blockIdx.x * 32;
  int k0 = blockIdx.y * 32;
  int tx = threadIdx.x;
  int ty = threadIdx.y;
  for (int i = 0; i < 32; i += 8)
    tile[ty + i][tx] = wv[(long)(k0 + ty + i) * NDIM + n0 + tx];
  __syncthreads();
  for (int i = 0; i < 32; i += 8)
    Bt[(long)(n0 + ty + i) * KDIM + k0 + tx] = f2h(tile[tx][ty + i] * BSCL);
}

// ---------------- K2: per-token analytic scale -> A fp16 (= rcx * ASCL), cx2 ----------------
__global__ __launch_bounds__(256) void prep_x(const float* __restrict__ x, const float* __restrict__ cptr,
                                              unsigned short* __restrict__ A, float* __restrict__ cx2out,
                                              float Rbeta) {
  int w = threadIdx.x >> 6, lane = threadIdx.x & 63;
  int tok = blockIdx.x * 4 + w;
  const float4* x4 = (const float4*)x;
  float4 v[NSTK];
  float ss[NSTK];
  for (int s = 0; s < NSTK; s++) {
    float4 t = x4[(long)tok * 256 + s * 64 + lane];
    v[s] = t;
    float d = t.x * t.x + t.y * t.y + t.z * t.z + t.w * t.w;
    for (int m = 1; m < 64; m <<= 1) d += __shfl_xor(d, m);
    ss[s] = d;
  }
  float c = cptr[0];
  float rc = sqrtf(c);
  float h[NSTK], un[NSTK], hs2 = 0.0f;
  for (int s = 0; s < NSTK; s++) {
    un[s] = fmaxf(sqrtf(ss[s]), 1e-15f);
    float t1 = fminf(tanhf(rc * un[s]), 0.996f);
    float z = fminf(t1, 1.0f - 1e-7f);
    float hh = 0.5f * logf((1.0f + z) / (1.0f - z));
    h[s] = hh;
    hs2 += hh * hh;
  }
  float sqh = sqrtf(hs2);
  float uwrc = Rbeta * sqh;
  float t2 = fminf(tanhf(uwrc), 0.996f);
  if (lane == 0) cx2out[tok] = t2 * t2;
  float denomw = fmaxf(uwrc, rc * 1e-15f);
  for (int s = 0; s < NSTK; s++) {
    float scl = ASCL * Rbeta * h[s] * t2 / (un[s] * denomw);
    float4 t = v[s];
    ushort4 pk = make_ushort4(f2h(t.x * scl), f2h(t.y * scl), f2h(t.z * scl), f2h(t.w * scl));
    *(ushort4*)&A[(long)tok * KDIM + s * SDIM + lane * 4] = pk;
  }
}

// ---------------- K3: 256x256 8-phase fp16 MFMA GEMM ----------------
#define BK 64
#define NKT (KDIM / BK)  // 16

#define GLDS16(g, l)                                                              \
  __builtin_amdgcn_global_load_lds((const __attribute__((address_space(1))) void*)(g), \
                                   (__attribute__((address_space(3))) void*)(l), 16, 0, 0)

#define PH_BARRIER __builtin_amdgcn_s_barrier()
#define PRIO1 __builtin_amdgcn_s_setprio(1)
#define PRIO0 __builtin_amdgcn_s_setprio(0)
#define LGKM0                                                  \
  do {                                                         \
    asm volatile("s_waitcnt lgkmcnt(0)" ::: "memory");         \
    __builtin_amdgcn_sched_barrier(0);                         \
  } while (0)
#define VMCNT4 asm volatile("s_waitcnt vmcnt(4)" ::: "memory")
#define VMCNT0 asm volatile("s_waitcnt vmcnt(0)" ::: "memory")

#define ISSUE_A(T, H)                                                        \
  do {                                                                       \
    const unsigned short* _s = Asrc + (long)(H) * (128 * KDIM) + (T) * BK;   \
    unsigned char* _d = lds + (((T) & 1) * 32768 + (H) * 16384) + tid * 16;  \
    GLDS16(_s, _d);                                                          \
    GLDS16(_s + 64 * KDIM, _d + 8192);                                       \
  } while (0)
#define ISSUE_B(T, H)                                                        \
  do {                                                                       \
    const unsigned short* _s = Bsrc + (long)(H) * (128 * KDIM) + (T) * BK;   \
    unsigned char* _d = lds + 65536 + (((T) & 1) * 32768 + (H) * 16384) + tid * 16; \
    GLDS16(_s, _d);                                                          \
    GLDS16(_s + 64 * KDIM, _d + 8192);                                       \
  } while (0)

#define READ_A4(BUFOFF, FMB, KS)                                             \
  _Pragma("unroll") for (int fm = 0; fm < 4; ++fm)                           \
    aF[fm][KS] = *(const f16x8*)(lds + (BUFOFF) + aBase + ((FMB) + fm) * 2048 + chunk[KS]);
#define READ_B4(BUFOFF, KS)                                                  \
  _Pragma("unroll") for (int fn = 0; fn < 4; ++fn)                           \
    bF[fn][KS] = *(const f16x8*)(lds + 65536 + (BUFOFF) + bBase + fn * 2048 + chunk[KS]);

#define MFMA_PH(FM0, KS)                                                     \
  _Pragma("unroll") for (int fi = 0; fi < 4; ++fi)                           \
    _Pragma("unroll") for (int fj = 0; fj < 4; ++fj)                         \
      acc[(FM0) + fi][fj] = __builtin_amdgcn_mfma_f32_16x16x32_f16(          \
          aF[fi][KS], bF[fj][KS], acc[(FM0) + fi][fj], 0, 0, 0);

#define TILE(BUFOFF, T, GA, GB, VMODE)                                       \
  do {                                                                       \
    READ_A4(BUFOFF, 0, 0); READ_B4(BUFOFF, 0);                               \
    if (GA) ISSUE_A((T) + 1, 0);                                             \
    PH_BARRIER; LGKM0;                                                       \
    PRIO1; MFMA_PH(0, 0); PRIO0;                                             \
    PH_BARRIER;                                                              \
    READ_A4(BUFOFF, 0, 1); READ_B4(BUFOFF, 1);                               \
    if (GA) ISSUE_A((T) + 1, 1);                                             \
    PH_BARRIER; LGKM0;                                                       \
    PRIO1; MFMA_PH(0, 1); PRIO0;                                             \
    PH_BARRIER;                                                              \
    READ_A4(BUFOFF, 4, 0);                                                   \
    if (GB) ISSUE_B((T) + 2, 0);                                             \
    PH_BARRIER; LGKM0;                                                       \
    PRIO1; MFMA_PH(4, 0); PRIO0;                                             \
    PH_BARRIER;                                                              \
    READ_A4(BUFOFF, 4, 1);                                                   \
    if (GB) ISSUE_B((T) + 2, 1);                                             \
    if ((VMODE) == 0) { VMCNT4; } else if ((VMODE) == 1) { VMCNT0; }         \
    PH_BARRIER; LGKM0;                                                       \
    PRIO1; MFMA_PH(4, 1); PRIO0;                                             \
    PH_BARRIER;                                                              \
  } while (0)

template <int F16S>
__global__ __launch_bounds__(512, 2) void gemm_ep(const unsigned short* __restrict__ A,
                                                  const unsigned short* __restrict__ Bt,
                                                  const float* __restrict__ cx2,
                                                  const float* __restrict__ colp,
                                                  const float* __restrict__ cptr,
                                                  float* __restrict__ outY,
                                                  unsigned short* __restrict__ y16,
                                                  float* __restrict__ partials) {
  __shared__ __attribute__((aligned(16))) unsigned char lds[131072];
  int tid = threadIdx.x;
  int lane = tid & 63, w = tid >> 6;
  int wm = w >> 2, wn = w & 3;  // 2 x 4 waves; per-wave out 128x64
  int g = lane >> 4, r = lane & 15;
  int bid = blockIdx.x;
  int tile_n = bid & 7, tile_m = bid >> 3;
  int m0 = tile_m * 256, n0 = tile_n * 256;

  int srow = tid >> 3;
  int csrc = ((tid & 7) ^ (srow & 7)) << 3;
  const unsigned short* Asrc = A + (long)(m0 + srow) * KDIM + csrc;
  const unsigned short* Bsrc = Bt + (long)(n0 + srow) * KDIM + csrc;

  int aBase = wm * 16384 + r * 128;
  int bBase = (wn >> 1) * 16384 + (wn & 1) * 8192 + r * 128;
  int chunk[2];
  chunk[0] = ((0 * 4 + g) ^ (r & 7)) * 16;
  chunk[1] = ((1 * 4 + g) ^ (r & 7)) * 16;

  f32x4 acc[8][4];
#pragma unroll
  for (int i = 0; i < 8; i++)
#pragma unroll
    for (int j = 0; j < 4; j++) acc[i][j] = (f32x4){0.f, 0.f, 0.f, 0.f};
  f16x8 aF[4][2], bF[4][2];

  ISSUE_A(0, 0); ISSUE_A(0, 1); ISSUE_B(0, 0); ISSUE_B(0, 1);
  ISSUE_B(1, 0); ISSUE_B(1, 1);
  VMCNT4;
  PH_BARRIER;

#pragma unroll 1
  for (int it = 0; it < 7; ++it) {
    TILE(0, 2 * it, 1, 1, 0);
    TILE(32768, 2 * it + 1, 1, 1, 0);
  }
  TILE(0, 14, 1, 0, 1);
  TILE(32768, 15, 0, 0, 2);

  // epilogue E1: y = sinh(2*wg*arsinh(num/(1-cx2)))/rc (unscaled), partials;
  // y -> wave-private LDS (bank-swizzled), then E2: coalesced 16B stores.
  float c = cptr[0];
  float rc = sqrtf(c);
  float inv_rc = 1.0f / rc;
  const float4* cp4 = (const float4*)colp;
  int tn4 = tile_n * 4 + wn;
  unsigned char* wlds = &lds[w * 16384];
#pragma unroll
  for (int fm = 0; fm < 8; ++fm) {
#pragma unroll
    for (int q = 0; q < 4; ++q) {
      int rw = fm * 16 + g * 4 + q;  // row within wave tile, 0..127
      int row = m0 + wm * 128 + rw;
      float cx = cx2[row];
      float onec = 1.0f + cx;
      float rdn = 1.0f / fmaxf(1.0f - cx, 1e-15f);
      float rs = 0.0f;
      int rmask = ((rw >> 1) & 7) << 3;
#pragma unroll
      for (int fn = 0; fn < 4; ++fn) {
        int cw = fn * 16 + r;  // col within wave tile, 0..63
        int col = n0 + wn * 64 + cw;
        float4 cp = cp4[col];
        float dot = acc[fm][fn][q];
        float num = fmaf(dot, cp.x, -onec * cp.y);
        float u = num * rdn;
        float au = fabsf(u);
        // v_log_f32 / v_exp_f32 are base-2: arsinh|u| = ln2 * log2(|u|+sqrt(u^2+1))
        float l2 = __builtin_amdgcn_logf(au + sqrtf(fmaf(au, au, 1.0f)));
        float ex = __builtin_amdgcn_exp2f(cp.z * l2);  // exp2(2*wg*log2(.)) = (.)^(2*wg)... cp.z pre-scaled
        float exi = __builtin_amdgcn_rcpf(ex);
        float y = copysignf(0.5f * (ex - exi) * inv_rc, u);
        if (F16S) {
          *(unsigned short*)(wlds + rw * 128 + ((cw ^ rmask) << 1)) = f2h(y);
        } else {
          outY[(long)row * NDIM + col] = y;
        }
        rs = fmaf(y, y, rs);
      }
      rs += __shfl_xor(rs, 1);
      rs += __shfl_xor(rs, 2);
      rs += __shfl_xor(rs, 4);
      rs += __shfl_xor(rs, 8);
      if (r == 0) partials[(long)row * 32 + tn4] = rs;
    }
  }
  if (F16S) {
    asm volatile("s_waitcnt lgkmcnt(0)" ::: "memory");
    __builtin_amdgcn_sched_barrier(0);
    int rsub = lane >> 3;
    int cw0 = (lane & 7) * 8;
#pragma unroll
    for (int it2 = 0; it2 < 16; ++it2) {
      int rw = it2 * 8 + rsub;
      int rmask = ((rw >> 1) & 7) << 3;
      f16x8 v = *(const f16x8*)(wlds + rw * 128 + ((cw0 ^ rmask) << 1));
      *(f16x8*)&y16[(long)(m0 + wm * 128 + rw) * NDIM + n0 + wn * 64 + cw0] = v;
    }
  }
}

// ---------------- K4a: row scale from partials, apply from fp16 scratch ----------------
__global__ __launch_bounds__(256) void finalize16(const unsigned short* __restrict__ y16,
                                                  const float* __restrict__ partials,
                                                  const float* __restrict__ cptr,
                                                  float* __restrict__ out) {
  int w = threadIdx.x >> 6, lane = threadIdx.x & 63;
  int row = blockIdx.x * 4 + w;
  float p = (lane < 32) ? partials[(long)row * 32 + lane] : 0.0f;
  for (int m = 1; m < 64; m <<= 1) p += __shfl_xor(p, m);
  float c = cptr[0];
  float S = p;
  float denom = 1.0f + sqrtf(fmaf(c, S, 1.0f));
  float nv = fmaxf(sqrtf(S) / denom, 1e-15f);
  float maxn = (c > 0.0f) ? 0.996f / sqrtf(fmaxf(c, 1e-15f)) : 1e15f;
  float scl = (nv > maxn) ? (maxn / (nv * denom)) : (1.0f / denom);
  const f16x8* yr = (const f16x8*)(y16 + (long)row * NDIM);
  float4* o4 = (float4*)(out + (long)row * NDIM);
#pragma unroll
  for (int it = 0; it < 4; ++it) {
    f16x8 v = yr[it * 64 + lane];
    float4 a, b;
    a.x = (float)v[0] * scl; a.y = (float)v[1] * scl;
    a.z = (float)v[2] * scl; a.w = (float)v[3] * scl;
    b.x = (float)v[4] * scl; b.y = (float)v[5] * scl;
    b.z = (float)v[6] * scl; b.w = (float)v[7] * scl;
    o4[(it * 64 + lane) * 2] = a;
    o4[(it * 64 + lane) * 2 + 1] = b;
  }
}

// ---------------- K4b: fallback, in place on fp32 d_out ----------------
__global__ __launch_bounds__(256) void finalize32(float* __restrict__ out,
                                                  const float* __restrict__ partials,
                                                  const float* __restrict__ cptr) {
  int w = threadIdx.x >> 6, lane = threadIdx.x & 63;
  int row = blockIdx.x * 4 + w;
  float p = (lane < 32) ? partials[(long)row * 32 + lane] : 0.0f;
  for (int m = 1; m < 64; m <<= 1) p += __shfl_xor(p, m);
  float c = cptr[0];
  float S = p;
  float denom = 1.0f + sqrtf(fmaf(c, S, 1.0f));
  float nv = fmaxf(sqrtf(S) / denom, 1e-15f);
  float maxn = (c > 0.0f) ? 0.996f / sqrtf(fmaxf(c, 1e-15f)) : 1e15f;
  float scl = (nv > maxn) ? (maxn / (nv * denom)) : (1.0f / denom);
  float4* o4 = (float4*)(out + (long)row * NDIM);
  for (int it = 0; it < NDIM / 256; ++it) {
    float4 v = o4[it * 64 + lane];
    v.x *= scl; v.y *= scl; v.z *= scl; v.w *= scl;
    o4[it * 64 + lane] = v;
  }
}

extern "C" void kernel_launch(void* const* d_in, const int* in_sizes, int n_in,
                              void* d_out, int out_size, void* d_ws, size_t ws_size,
                              hipStream_t stream) {
  const float* x = (const float*)d_in[0];
  const float* wg = (const float*)d_in[1];
  const float* wv = (const float*)d_in[2];
  const float* bias = (const float*)d_in[3];
  const float* cpt = (const float*)d_in[4];
  float* out = (float*)d_out;

  char* ws = (char*)d_ws;
  unsigned short* A = (unsigned short*)ws;                    // 33,554,432 B
  unsigned short* Bt = (unsigned short*)(ws + 33554432);      //  4,194,304 B
  float* cx2 = (float*)(ws + 37748736);                       //     65,536 B
  float* colp = (float*)(ws + 37814272);                      //     32,768 B
  float* parts = (float*)(ws + 37847040);                     //  2,097,152 B
  unsigned short* Y16 = (unsigned short*)(ws + 39944192);     // 67,108,864 B
  const size_t NEED_F16S = 39944192ull + 67108864ull;

  double lbni = lgamma(128.0) + lgamma(0.5) - lgamma(128.5);
  double lbn = lgamma(512.0) + lgamma(0.5) - lgamma(512.5);
  float Rbeta = (float)exp(lbn - lbni);

  prep_cols<<<8, 256, 0, stream>>>(wg, bias, cpt, colp);
  transpose_w<<<dim3(64, 32), dim3(32, 8), 0, stream>>>(wv, Bt);
  prep_x<<<4096, 256, 0, stream>>>(x, cpt, A, cx2, Rbeta);
  if (ws_size >= NEED_F16S) {
    gemm_ep<1><<<512, 512, 0, stream>>>(A, Bt, cx2, colp, cpt, out, Y16, parts);
    finalize16<<<4096, 256, 0, stream>>>(Y16, parts, cpt, out);
  } else {
    gemm_ep<0><<<512, 512, 0, stream>>>(A, Bt, cx2, colp, cpt, out, Y16, parts);
    finalize32<<<4096, 256, 0, stream>>>(out, parts, cpt);
  }
}

// Round 8
// 172.738 us; speedup vs baseline: 2.3183x; 1.0038x over previous
//
#include <hip/hip_runtime.h>
#include <hip/hip_bf16.h>
#include <hip/hip_fp16.h>
#include <cmath>

#define NTOK 16384
#define KDIM 1024
#define NDIM 2048
#define NSTK 4
#define SDIM 256

typedef __attribute__((ext_vector_type(8))) _Float16 f16x8;
typedef __attribute__((ext_vector_type(4))) float f32x4;

static __device__ __forceinline__ unsigned short f2h(float f) {
  union { _Float16 h; unsigned short u; } v;
  v.h = (_Float16)f;
  return v.u;
}

#define ASCL 16.0f
#define BSCL 32.0f
#define ABSCL 512.0f  // ASCL*BSCL

// ---------------- K0: per-output-column params ----------------
__global__ void prep_cols(const float* __restrict__ wg, const float* __restrict__ bias,
                          const float* __restrict__ cptr, float* __restrict__ colp) {
  int j = blockIdx.x * 256 + threadIdx.x;
  if (j >= NDIM) return;
  float c = cptr[0];
  float rc = sqrtf(c);
  float w = wg[j];
  float invn = 1.0f / fmaxf(w, 1e-15f);
  float drcr = 2.0f * rc * bias[j];
  float ed = expf(drcr);
  float edi = 1.0f / ed;
  float coshd = 0.5f * (ed + edi);
  float sinhd = 0.5f * (ed - edi);
  colp[4 * j + 0] = 2.0f * invn * coshd / ABSCL;
  colp[4 * j + 1] = sinhd;
  colp[4 * j + 2] = 2.0f * w;
  colp[4 * j + 3] = 0.0f;
}

// ---------------- K1: transpose weight_v [K][N] -> Bt fp16 [N][K] (x BSCL) ----------------
__global__ void transpose_w(const float* __restrict__ wv, unsigned short* __restrict__ Bt) {
  __shared__ float tile[32][33];
  int n0 = blockIdx.x * 32;
  int k0 = blockIdx.y * 32;
  int tx = threadIdx.x;
  int ty = threadIdx.y;
  for (int i = 0; i < 32; i += 8)
    tile[ty + i][tx] = wv[(long)(k0 + ty + i) * NDIM + n0 + tx];
  __syncthreads();
  for (int i = 0; i < 32; i += 8)
    Bt[(long)(n0 + ty + i) * KDIM + k0 + tx] = f2h(tile[tx][ty + i] * BSCL);
}

// ---------------- K2: per-token analytic scale -> A fp16 (= rcx * ASCL), cx2 ----------------
__global__ __launch_bounds__(256) void prep_x(const float* __restrict__ x, const float* __restrict__ cptr,
                                              unsigned short* __restrict__ A, float* __restrict__ cx2out,
                                              float Rbeta) {
  int w = threadIdx.x >> 6, lane = threadIdx.x & 63;
  int tok = blockIdx.x * 4 + w;
  const float4* x4 = (const float4*)x;
  float4 v[NSTK];
  float ss[NSTK];
  for (int s = 0; s < NSTK; s++) {
    float4 t = x4[(long)tok * 256 + s * 64 + lane];
    v[s] = t;
    float d = t.x * t.x + t.y * t.y + t.z * t.z + t.w * t.w;
    for (int m = 1; m < 64; m <<= 1) d += __shfl_xor(d, m);
    ss[s] = d;
  }
  float c = cptr[0];
  float rc = sqrtf(c);
  float h[NSTK], un[NSTK], hs2 = 0.0f;
  for (int s = 0; s < NSTK; s++) {
    un[s] = fmaxf(sqrtf(ss[s]), 1e-15f);
    float t1 = fminf(tanhf(rc * un[s]), 0.996f);
    float z = fminf(t1, 1.0f - 1e-7f);
    float hh = 0.5f * logf((1.0f + z) / (1.0f - z));
    h[s] = hh;
    hs2 += hh * hh;
  }
  float sqh = sqrtf(hs2);
  float uwrc = Rbeta * sqh;
  float t2 = fminf(tanhf(uwrc), 0.996f);
  if (lane == 0) cx2out[tok] = t2 * t2;
  float denomw = fmaxf(uwrc, rc * 1e-15f);
  for (int s = 0; s < NSTK; s++) {
    float scl = ASCL * Rbeta * h[s] * t2 / (un[s] * denomw);
    float4 t = v[s];
    ushort4 pk = make_ushort4(f2h(t.x * scl), f2h(t.y * scl), f2h(t.z * scl), f2h(t.w * scl));
    *(ushort4*)&A[(long)tok * KDIM + s * SDIM + lane * 4] = pk;
  }
}

// ---------------- K3: 256x256 pipelined fp16 MFMA GEMM (1 barrier/phase) ----------------
#define BK 64
#define NKT (KDIM / BK)  // 16

#define GLDS16(g, l)                                                              \
  __builtin_amdgcn_global_load_lds((const __attribute__((address_space(1))) void*)(g), \
                                   (__attribute__((address_space(3))) void*)(l), 16, 0, 0)

#define PH_BARRIER __builtin_amdgcn_s_barrier()
#define PRIO1 __builtin_amdgcn_s_setprio(1)
#define PRIO0 __builtin_amdgcn_s_setprio(0)
#define LGKM0                                                  \
  do {                                                         \
    asm volatile("s_waitcnt lgkmcnt(0)" ::: "memory");         \
    __builtin_amdgcn_sched_barrier(0);                         \
  } while (0)
#define VMCNT4 asm volatile("s_waitcnt vmcnt(4)" ::: "memory")
#define VMCNT2 asm volatile("s_waitcnt vmcnt(2)" ::: "memory")
#define VMCNT0 asm volatile("s_waitcnt vmcnt(0)" ::: "memory")

#define ISSUE_A(T, H)                                                        \
  do {                                                                       \
    const unsigned short* _s = Asrc + (long)(H) * (128 * KDIM) + (T) * BK;   \
    unsigned char* _d = lds + (((T) & 1) * 32768 + (H) * 16384) + tid * 16;  \
    GLDS16(_s, _d);                                                          \
    GLDS16(_s + 64 * KDIM, _d + 8192);                                       \
  } while (0)
#define ISSUE_B(T, H)                                                        \
  do {                                                                       \
    const unsigned short* _s = Bsrc + (long)(H) * (128 * KDIM) + (T) * BK;   \
    unsigned char* _d = lds + 65536 + (((T) & 1) * 32768 + (H) * 16384) + tid * 16; \
    GLDS16(_s, _d);                                                          \
    GLDS16(_s + 64 * KDIM, _d + 8192);                                       \
  } while (0)

// fragment reads (4 x ds_read_b128 each). A-lo = fm0-3, A-hi = fm4-7 (reuse aF regs).
#define READ_AL(BUFOFF, KS)                                                  \
  _Pragma("unroll") for (int fm = 0; fm < 4; ++fm)                           \
    aF[fm][KS] = *(const f16x8*)(lds + (BUFOFF) + aBase + fm * 2048 + chunk[KS]);
#define READ_AH(BUFOFF, KS)                                                  \
  _Pragma("unroll") for (int fm = 0; fm < 4; ++fm)                           \
    aF[fm][KS] = *(const f16x8*)(lds + (BUFOFF) + aBase + (4 + fm) * 2048 + chunk[KS]);
#define READ_BN(BUFOFF, KS)                                                  \
  _Pragma("unroll") for (int fn = 0; fn < 4; ++fn)                           \
    bF[fn][KS] = *(const f16x8*)(lds + 65536 + (BUFOFF) + bBase + fn * 2048 + chunk[KS]);

#define MFMA_PH(FM0, KS)                                                     \
  _Pragma("unroll") for (int fi = 0; fi < 4; ++fi)                           \
    _Pragma("unroll") for (int fj = 0; fj < 4; ++fj)                         \
      acc[(FM0) + fi][fj] = __builtin_amdgcn_mfma_f32_16x16x32_f16(          \
          aF[fi][KS], bF[fj][KS], acc[(FM0) + fi][fj], 0, 0, 0);

// Pipelined tile: each phase = {lgkm0; MFMA (prev reads); issue next reads + stage; barrier}.
// FIFO vmcnt accounting (2 loads per ISSUE):
//   enter tile: B(T+1) 4 outstanding. Ph1 +A(T+1,0)=6. Ph2 +A(T+1,1)=8 -> vmcnt(4): B(T+1) landed
//   (read at Ph3/Ph4). Ph3 +B(T+2,0)=6 -> vmcnt(2): A(T+1) landed (read at Ph4). Ph4 +B(T+2,1)=4.
// VM3: 2 -> vmcnt(2); 0 -> vmcnt(0) (T=14, no B stage); -1 -> none (last tile).
#define TILE(BUFOFF, T, SA, SB, RDN, VM2, VM3)                               \
  do {                                                                       \
    LGKM0;                                                                   \
    PRIO1; MFMA_PH(0, 0); PRIO0;                                             \
    READ_AH(BUFOFF, 0);                                                      \
    if (SA) ISSUE_A((T) + 1, 0);                                             \
    PH_BARRIER;                                                              \
    LGKM0;                                                                   \
    PRIO1; MFMA_PH(0, 1); PRIO0;                                             \
    READ_AH(BUFOFF, 1);                                                      \
    if (SA) ISSUE_A((T) + 1, 1);                                             \
    if (VM2) { VMCNT4; }                                                     \
    PH_BARRIER;                                                              \
    LGKM0;                                                                   \
    PRIO1; MFMA_PH(4, 0); PRIO0;                                             \
    if (RDN) READ_BN((BUFOFF) ^ 32768, 0);                                   \
    if (SB) ISSUE_B((T) + 2, 0);                                             \
    if ((VM3) == 2) { VMCNT2; } else if ((VM3) == 0) { VMCNT0; }             \
    PH_BARRIER;                                                              \
    LGKM0;                                                                   \
    PRIO1; MFMA_PH(4, 1); PRIO0;                                             \
    if (RDN) {                                                               \
      READ_AL((BUFOFF) ^ 32768, 0);                                          \
      READ_AL((BUFOFF) ^ 32768, 1);                                          \
      READ_BN((BUFOFF) ^ 32768, 1);                                          \
    }                                                                        \
    if (SB) ISSUE_B((T) + 2, 1);                                             \
    PH_BARRIER;                                                              \
  } while (0)

template <int F16S>
__global__ __launch_bounds__(512, 2) void gemm_ep(const unsigned short* __restrict__ A,
                                                  const unsigned short* __restrict__ Bt,
                                                  const float* __restrict__ cx2,
                                                  const float* __restrict__ colp,
                                                  const float* __restrict__ cptr,
                                                  float* __restrict__ outY,
                                                  unsigned short* __restrict__ y16,
                                                  float* __restrict__ partials) {
  __shared__ __attribute__((aligned(16))) unsigned char lds[131072];
  int tid = threadIdx.x;
  int lane = tid & 63, w = tid >> 6;
  int wm = w >> 2, wn = w & 3;  // 2 x 4 waves; per-wave out 128x64
  int g = lane >> 4, r = lane & 15;
  int bid = blockIdx.x;
  int tile_n = bid & 7, tile_m = bid >> 3;
  int m0 = tile_m * 256, n0 = tile_n * 256;

  int srow = tid >> 3;
  int csrc = ((tid & 7) ^ (srow & 7)) << 3;
  const unsigned short* Asrc = A + (long)(m0 + srow) * KDIM + csrc;
  const unsigned short* Bsrc = Bt + (long)(n0 + srow) * KDIM + csrc;

  int aBase = wm * 16384 + r * 128;
  int bBase = (wn >> 1) * 16384 + (wn & 1) * 8192 + r * 128;
  int chunk[2];
  chunk[0] = ((0 * 4 + g) ^ (r & 7)) * 16;
  chunk[1] = ((1 * 4 + g) ^ (r & 7)) * 16;

  f32x4 acc[8][4];
#pragma unroll
  for (int i = 0; i < 8; i++)
#pragma unroll
    for (int j = 0; j < 4; j++) acc[i][j] = (f32x4){0.f, 0.f, 0.f, 0.f};
  f16x8 aF[4][2], bF[4][2];

  // prologue: stage tile0 fully + tile1 B; land tile0 (vmcnt4 leaves B(1) in flight);
  // pre-read tile0's A-lo + B fragments (the pipeline's phase -1 reads).
  ISSUE_A(0, 0); ISSUE_A(0, 1); ISSUE_B(0, 0); ISSUE_B(0, 1);
  ISSUE_B(1, 0); ISSUE_B(1, 1);
  VMCNT4;
  PH_BARRIER;
  READ_AL(0, 0); READ_AL(0, 1); READ_BN(0, 0); READ_BN(0, 1);

#pragma unroll 1
  for (int it = 0; it < 7; ++it) {
    TILE(0, 2 * it, 1, 1, 1, 1, 2);
    TILE(32768, 2 * it + 1, 1, 1, 1, 1, 2);
  }
  TILE(0, 14, 1, 0, 1, 1, 0);        // stage A(15); drain all loads (vmcnt 0)
  TILE(32768, 15, 0, 0, 0, 0, -1);   // last tile: no stages, no pre-reads

  // epilogue E1: y = sinh(2*wg*arsinh(num/(1-cx2)))/rc (unscaled), partials;
  // y -> wave-private LDS (bank-swizzled), then E2: coalesced 16B stores.
  float c = cptr[0];
  float rc = sqrtf(c);
  float inv_rc = 1.0f / rc;
  const float4* cp4 = (const float4*)colp;
  int tn4 = tile_n * 4 + wn;
  unsigned char* wlds = &lds[w * 16384];
#pragma unroll
  for (int fm = 0; fm < 8; ++fm) {
#pragma unroll
    for (int q = 0; q < 4; ++q) {
      int rw = fm * 16 + g * 4 + q;  // row within wave tile, 0..127
      int row = m0 + wm * 128 + rw;
      float cx = cx2[row];
      float onec = 1.0f + cx;
      float rdn = 1.0f / fmaxf(1.0f - cx, 1e-15f);
      float rs = 0.0f;
      int rmask = ((rw >> 1) & 7) << 3;
#pragma unroll
      for (int fn = 0; fn < 4; ++fn) {
        int cw = fn * 16 + r;  // col within wave tile, 0..63
        int col = n0 + wn * 64 + fn * 16 + r;
        float4 cp = cp4[col];
        float dot = acc[fm][fn][q];
        float num = fmaf(dot, cp.x, -onec * cp.y);
        float u = num * rdn;
        float au = fabsf(u);
        float l2 = __builtin_amdgcn_logf(au + sqrtf(fmaf(au, au, 1.0f)));
        float ex = __builtin_amdgcn_exp2f(cp.z * l2);
        float exi = __builtin_amdgcn_rcpf(ex);
        float y = copysignf(0.5f * (ex - exi) * inv_rc, u);
        if (F16S) {
          *(unsigned short*)(wlds + rw * 128 + ((cw ^ rmask) << 1)) = f2h(y);
        } else {
          outY[(long)row * NDIM + col] = y;
        }
        rs = fmaf(y, y, rs);
      }
      rs += __shfl_xor(rs, 1);
      rs += __shfl_xor(rs, 2);
      rs += __shfl_xor(rs, 4);
      rs += __shfl_xor(rs, 8);
      if (r == 0) partials[(long)row * 32 + tn4] = rs;
    }
  }
  if (F16S) {
    asm volatile("s_waitcnt lgkmcnt(0)" ::: "memory");
    __builtin_amdgcn_sched_barrier(0);
    int rsub = lane >> 3;
    int cw0 = (lane & 7) * 8;
#pragma unroll
    for (int it2 = 0; it2 < 16; ++it2) {
      int rw = it2 * 8 + rsub;
      int rmask = ((rw >> 1) & 7) << 3;
      f16x8 v = *(const f16x8*)(wlds + rw * 128 + ((cw0 ^ rmask) << 1));
      *(f16x8*)&y16[(long)(m0 + wm * 128 + rw) * NDIM + n0 + wn * 64 + cw0] = v;
    }
  }
}

// ---------------- K4a: row scale from partials, apply from fp16 scratch ----------------
__global__ __launch_bounds__(256) void finalize16(const unsigned short* __restrict__ y16,
                                                  const float* __restrict__ partials,
                                                  const float* __restrict__ cptr,
                                                  float* __restrict__ out) {
  int w = threadIdx.x >> 6, lane = threadIdx.x & 63;
  int row = blockIdx.x * 4 + w;
  float p = (lane < 32) ? partials[(long)row * 32 + lane] : 0.0f;
  for (int m = 1; m < 64; m <<= 1) p += __shfl_xor(p, m);
  float c = cptr[0];
  float S = p;
  float denom = 1.0f + sqrtf(fmaf(c, S, 1.0f));
  float nv = fmaxf(sqrtf(S) / denom, 1e-15f);
  float maxn = (c > 0.0f) ? 0.996f / sqrtf(fmaxf(c, 1e-15f)) : 1e15f;
  float scl = (nv > maxn) ? (maxn / (nv * denom)) : (1.0f / denom);
  const f16x8* yr = (const f16x8*)(y16 + (long)row * NDIM);
  float4* o4 = (float4*)(out + (long)row * NDIM);
#pragma unroll
  for (int it = 0; it < 4; ++it) {
    f16x8 v = yr[it * 64 + lane];
    float4 a, b;
    a.x = (float)v[0] * scl; a.y = (float)v[1] * scl;
    a.z = (float)v[2] * scl; a.w = (float)v[3] * scl;
    b.x = (float)v[4] * scl; b.y = (float)v[5] * scl;
    b.z = (float)v[6] * scl; b.w = (float)v[7] * scl;
    o4[(it * 64 + lane) * 2] = a;
    o4[(it * 64 + lane) * 2 + 1] = b;
  }
}

// ---------------- K4b: fallback, in place on fp32 d_out ----------------
__global__ __launch_bounds__(256) void finalize32(float* __restrict__ out,
                                                  const float* __restrict__ partials,
                                                  const float* __restrict__ cptr) {
  int w = threadIdx.x >> 6, lane = threadIdx.x & 63;
  int row = blockIdx.x * 4 + w;
  float p = (lane < 32) ? partials[(long)row * 32 + lane] : 0.0f;
  for (int m = 1; m < 64; m <<= 1) p += __shfl_xor(p, m);
  float c = cptr[0];
  float S = p;
  float denom = 1.0f + sqrtf(fmaf(c, S, 1.0f));
  float nv = fmaxf(sqrtf(S) / denom, 1e-15f);
  float maxn = (c > 0.0f) ? 0.996f / sqrtf(fmaxf(c, 1e-15f)) : 1e15f;
  float scl = (nv > maxn) ? (maxn / (nv * denom)) : (1.0f / denom);
  float4* o4 = (float4*)(out + (long)row * NDIM);
  for (int it = 0; it < NDIM / 256; ++it) {
    float4 v = o4[it * 64 + lane];
    v.x *= scl; v.y *= scl; v.z *= scl; v.w *= scl;
    o4[it * 64 + lane] = v;
  }
}

extern "C" void kernel_launch(void* const* d_in, const int* in_sizes, int n_in,
                              void* d_out, int out_size, void* d_ws, size_t ws_size,
                              hipStream_t stream) {
  const float* x = (const float*)d_in[0];
  const float* wg = (const float*)d_in[1];
  const float* wv = (const float*)d_in[2];
  const float* bias = (const float*)d_in[3];
  const float* cpt = (const float*)d_in[4];
  float* out = (float*)d_out;

  char* ws = (char*)d_ws;
  unsigned short* A = (unsigned short*)ws;                    // 33,554,432 B
  unsigned short* Bt = (unsigned short*)(ws + 33554432);      //  4,194,304 B
  float* cx2 = (float*)(ws + 37748736);                       //     65,536 B
  float* colp = (float*)(ws + 37814272);                      //     32,768 B
  float* parts = (float*)(ws + 37847040);                     //  2,097,152 B
  unsigned short* Y16 = (unsigned short*)(ws + 39944192);     // 67,108,864 B
  const size_t NEED_F16S = 39944192ull + 67108864ull;

  double lbni = lgamma(128.0) + lgamma(0.5) - lgamma(128.5);
  double lbn = lgamma(512.0) + lgamma(0.5) - lgamma(512.5);
  float Rbeta = (float)exp(lbn - lbni);

  prep_cols<<<8, 256, 0, stream>>>(wg, bias, cpt, colp);
  transpose_w<<<dim3(64, 32), dim3(32, 8), 0, stream>>>(wv, Bt);
  prep_x<<<4096, 256, 0, stream>>>(x, cpt, A, cx2, Rbeta);
  if (ws_size >= NEED_F16S) {
    gemm_ep<1><<<512, 512, 0, stream>>>(A, Bt, cx2, colp, cpt, out, Y16, parts);
    finalize16<<<4096, 256, 0, stream>>>(Y16, parts, cpt, out);
  } else {
    gemm_ep<0><<<512, 512, 0, stream>>>(A, Bt, cx2, colp, cpt, out, Y16, parts);
    finalize32<<<4096, 256, 0, stream>>>(out, parts, cpt);
  }
}